// Round 3
// baseline (1400.918 us; speedup 1.0000x reference)
//
#include <hip/hip_runtime.h>
#include <math.h>

#define N_NODES 100000
#define N_EDGES 1600000
#define C_DIM 40

#define BSZ 256                        // nodes per bucket
#define NB  ((N_NODES + BSZ - 1) / BSZ)   // 391 buckets
#define EB  4096                       // edges per hist/scatter block
#define NBE ((N_EDGES + EB - 1) / EB)  // 391 edge blocks

// ---------------- workspace layout (4-byte units) ----------------
#define OFF_DINV 0                      // float[100000]
#define OFF_BB   100000                 // int[NB+1] bucket bases
#define OFF_H    100392                 // int[NBE*NB] per-block histograms
#define OFF_BLB  253273                 // int[NBE*NB] per-(block,bucket) bases
#define OFF_REC  406154                 // int2[E] (even index -> 8B aligned)
#define OFF_H1   3606154                // float[N*64]; h2 aliases this
#define OFF_AGG1 10006154               // float[N*64]

__device__ inline float rlane(float v, int k) {
    return __int_as_float(__builtin_amdgcn_readlane(__float_as_int(v), k));
}

// ---------- per-block bucket histogram: H[b][j] ----------
__global__ __launch_bounds__(512) void k_hist2d(const int* __restrict__ ei, int* __restrict__ H) {
    __shared__ int bins[NB];
    int t = threadIdx.x, b = blockIdx.x;
    for (int i = t; i < NB; i += 512) bins[i] = 0;
    __syncthreads();
    int base = b * EB;
    for (int i = t; i < EB; i += 512) {
        int e = base + i;
        if (e < N_EDGES) atomicAdd(&bins[ei[N_EDGES + e] >> 8], 1);
    }
    __syncthreads();
    for (int i = t; i < NB; i += 512) H[b * NB + i] = bins[i];
}

// ---------- 2D scan: bucketBase[j] and blockBase[b][j] (1 block) ----------
__global__ __launch_bounds__(512) void k_scan2d(const int* __restrict__ H,
                                                int* __restrict__ bucketBase,
                                                int* __restrict__ blockBase) {
    __shared__ int sd[512];
    int t = threadIdx.x;
    int s = 0;
    if (t < NB)
        for (int b = 0; b < NBE; ++b) s += H[b * NB + t];
    sd[t] = (t < NB) ? s : 0;
    __syncthreads();
    for (int off = 1; off < 512; off <<= 1) {
        int v = (t >= off) ? sd[t - off] : 0;
        __syncthreads();
        sd[t] += v;
        __syncthreads();
    }
    int myBase = (t == 0) ? 0 : sd[t - 1];
    if (t < NB) bucketBase[t] = myBase;
    if (t == NB - 1) bucketBase[NB] = sd[t];
    if (t < NB) {
        int run = myBase;
        for (int b = 0; b < NBE; ++b) {
            blockBase[b * NB + t] = run;
            run += H[b * NB + t];
        }
    }
}

// ---------- scatter into bucket regions (no global atomics) ----------
__global__ __launch_bounds__(512) void k_scatter(const int* __restrict__ ei,
                                                 const float* __restrict__ w,
                                                 const int* __restrict__ blockBase,
                                                 int2* __restrict__ rec) {
    __shared__ int bases[NB];
    __shared__ int cur[NB];
    int t = threadIdx.x, b = blockIdx.x;
    for (int i = t; i < NB; i += 512) { bases[i] = blockBase[b * NB + i]; cur[i] = 0; }
    __syncthreads();
    int base = b * EB;
    for (int i = t; i < EB; i += 512) {
        int e = base + i;
        if (e < N_EDGES) {
            int s = ei[e], d = ei[N_EDGES + e];
            float wv = w[e];
            int bin = d >> 8;
            int pos = bases[bin] + atomicAdd(&cur[bin], 1);
            rec[pos] = make_int2(s | ((d & 255) << 17), __float_as_int(wv));
        }
    }
}

// ---------- per-bucket deg from records -> dinv ----------
__global__ __launch_bounds__(512) void k_deg(const int* __restrict__ bucketBase,
                                             const int2* __restrict__ rec,
                                             float* __restrict__ dinv) {
    __shared__ float s[BSZ];
    int t = threadIdx.x, b = blockIdx.x;
    if (t < BSZ) s[t] = 0.f;
    __syncthreads();
    int r0 = bucketBase[b], r1 = bucketBase[b + 1];
    for (int i = r0 + t; i < r1; i += 512) {
        int2 rv = rec[i];
        atomicAdd(&s[(rv.x >> 17) & 255], __int_as_float(rv.y));
    }
    __syncthreads();
    int node = b * BSZ + t;
    if (t < BSZ && node < N_NODES) dinv[node] = rsqrtf(1.f + s[t]);
}

// ---------- rewrite record payload w -> coeff ----------
__global__ __launch_bounds__(512) void k_coeff(const int* __restrict__ bucketBase,
                                               const float* __restrict__ dinv,
                                               int2* __restrict__ rec) {
    int t = threadIdx.x, b = blockIdx.x;
    int r0 = bucketBase[b], r1 = bucketBase[b + 1];
    for (int i = r0 + t; i < r1; i += 512) {
        int2 rv = rec[i];
        int src = rv.x & 0x1FFFF;
        int dst = b * BSZ + ((rv.x >> 17) & 255);
        float c = dinv[src] * __int_as_float(rv.y) * dinv[dst];
        rec[i] = make_int2(rv.x, __float_as_int(c));
    }
}

// ---------- h1 = x @ W1 : W column in regs, readlane broadcast ----------
__global__ __launch_bounds__(256) void k_mm1(const float* __restrict__ x,
                                             const float* __restrict__ W1,
                                             float* __restrict__ h1) {
    int t = threadIdx.x, lane = t & 63, wv = t >> 6;
    int wid = blockIdx.x * 4 + wv, nw = gridDim.x * 4;
    float Wc[64];
#pragma unroll
    for (int k = 0; k < 64; ++k) Wc[k] = W1[k * 64 + lane];
    for (int r0 = wid * 4; r0 < N_NODES; r0 += nw * 4) {
        float x0 = x[(r0 + 0) * 64 + lane];
        float x1 = x[(r0 + 1) * 64 + lane];
        float x2 = x[(r0 + 2) * 64 + lane];
        float x3 = x[(r0 + 3) * 64 + lane];
        float a0 = 0.f, a1 = 0.f, a2 = 0.f, a3 = 0.f;
#pragma unroll
        for (int k = 0; k < 64; ++k) {
            float wk = Wc[k];
            a0 = fmaf(rlane(x0, k), wk, a0);
            a1 = fmaf(rlane(x1, k), wk, a1);
            a2 = fmaf(rlane(x2, k), wk, a2);
            a3 = fmaf(rlane(x3, k), wk, a3);
        }
        h1[(r0 + 0) * 64 + lane] = a0;
        h1[(r0 + 1) * 64 + lane] = a1;
        h1[(r0 + 2) * 64 + lane] = a2;
        h1[(r0 + 3) * 64 + lane] = a3;
    }
}

// ---------- agg1: per-bucket LDS tile accumulation (64 KB tile) ----------
__global__ __launch_bounds__(512, 4) void k_agg1(const int* __restrict__ bucketBase,
                                                 const int2* __restrict__ rec,
                                                 const float* __restrict__ dinv,
                                                 const float* __restrict__ h1,
                                                 float* __restrict__ agg1) {
    __shared__ float tile[BSZ * 64];  // 65536 B
    int t = threadIdx.x, lane = t & 63, wv = t >> 6;  // 8 waves
    int b = blockIdx.x;
    for (int i = t; i < BSZ * 64; i += 512) tile[i] = 0.f;
    __syncthreads();
    int r0 = bucketBase[b], r1 = bucketBase[b + 1];
    int i = r0 + wv * 2;
    for (; i + 1 < r1; i += 16) {
        int2 ra = rec[i], rb = rec[i + 1];
        float va = h1[(ra.x & 0x1FFFF) * 64 + lane];
        float vb = h1[(rb.x & 0x1FFFF) * 64 + lane];
        atomicAdd(&tile[((ra.x >> 17) & 255) * 64 + lane], va * __int_as_float(ra.y));
        atomicAdd(&tile[((rb.x >> 17) & 255) * 64 + lane], vb * __int_as_float(rb.y));
    }
    if (i < r1) {
        int2 ra = rec[i];
        float va = h1[(ra.x & 0x1FFFF) * 64 + lane];
        atomicAdd(&tile[((ra.x >> 17) & 255) * 64 + lane], va * __int_as_float(ra.y));
    }
    __syncthreads();
    int nodes = min(BSZ, N_NODES - b * BSZ);
    for (int r = wv; r < nodes; r += 8) {
        int node = b * BSZ + r;
        float dn = dinv[node];
        agg1[node * 64 + lane] = tile[r * 64 + lane] + h1[node * 64 + lane] * dn * dn;
    }
}

// ---------- h2 = relu(agg1 + b1) @ W2 ----------
__global__ __launch_bounds__(256) void k_mm2(const float* __restrict__ agg1,
                                             const float* __restrict__ b1,
                                             const float* __restrict__ W2,
                                             float* __restrict__ h2) {
    int t = threadIdx.x, lane = t & 63, wv = t >> 6;
    int wid = blockIdx.x * 4 + wv, nw = gridDim.x * 4;
    bool act = lane < C_DIM;
    float Wc[64];
#pragma unroll
    for (int k = 0; k < 64; ++k) Wc[k] = act ? W2[k * C_DIM + lane] : 0.f;
    float bv = b1[lane];
    for (int r0 = wid * 4; r0 < N_NODES; r0 += nw * 4) {
        float x0 = fmaxf(agg1[(r0 + 0) * 64 + lane] + bv, 0.f);
        float x1 = fmaxf(agg1[(r0 + 1) * 64 + lane] + bv, 0.f);
        float x2 = fmaxf(agg1[(r0 + 2) * 64 + lane] + bv, 0.f);
        float x3 = fmaxf(agg1[(r0 + 3) * 64 + lane] + bv, 0.f);
        float a0 = 0.f, a1 = 0.f, a2 = 0.f, a3 = 0.f;
#pragma unroll
        for (int k = 0; k < 64; ++k) {
            float wk = Wc[k];
            a0 = fmaf(rlane(x0, k), wk, a0);
            a1 = fmaf(rlane(x1, k), wk, a1);
            a2 = fmaf(rlane(x2, k), wk, a2);
            a3 = fmaf(rlane(x3, k), wk, a3);
        }
        if (act) {
            h2[(r0 + 0) * C_DIM + lane] = a0;
            h2[(r0 + 1) * C_DIM + lane] = a1;
            h2[(r0 + 2) * C_DIM + lane] = a2;
            h2[(r0 + 3) * C_DIM + lane] = a3;
        }
    }
}

// ---------- agg2 + self-loop + bias + log_softmax (40 KB tile) ----------
__global__ __launch_bounds__(512, 4) void k_agg2(const int* __restrict__ bucketBase,
                                                 const int2* __restrict__ rec,
                                                 const float* __restrict__ dinv,
                                                 const float* __restrict__ h2,
                                                 const float* __restrict__ b2,
                                                 float* __restrict__ out) {
    __shared__ float tile[BSZ * C_DIM];  // 40960 B
    int t = threadIdx.x, lane = t & 63, wv = t >> 6;
    int b = blockIdx.x;
    bool act = lane < C_DIM;
    for (int i = t; i < BSZ * C_DIM; i += 512) tile[i] = 0.f;
    __syncthreads();
    int r0 = bucketBase[b], r1 = bucketBase[b + 1];
    int i = r0 + wv * 2;
    for (; i + 1 < r1; i += 16) {
        int2 ra = rec[i], rb = rec[i + 1];
        float va = act ? h2[(ra.x & 0x1FFFF) * C_DIM + lane] : 0.f;
        float vb = act ? h2[(rb.x & 0x1FFFF) * C_DIM + lane] : 0.f;
        if (act) {
            atomicAdd(&tile[((ra.x >> 17) & 255) * C_DIM + lane], va * __int_as_float(ra.y));
            atomicAdd(&tile[((rb.x >> 17) & 255) * C_DIM + lane], vb * __int_as_float(rb.y));
        }
    }
    if (i < r1) {
        int2 ra = rec[i];
        float va = act ? h2[(ra.x & 0x1FFFF) * C_DIM + lane] : 0.f;
        if (act) atomicAdd(&tile[((ra.x >> 17) & 255) * C_DIM + lane], va * __int_as_float(ra.y));
    }
    __syncthreads();
    int nodes = min(BSZ, N_NODES - b * BSZ);
    float bv = act ? b2[lane] : 0.f;
    for (int r = wv; r < nodes; r += 8) {
        int node = b * BSZ + r;
        float dn = dinv[node];
        float v = act ? tile[r * C_DIM + lane] + h2[node * C_DIM + lane] * dn * dn + bv
                      : -INFINITY;
        float m = v;
#pragma unroll
        for (int off = 32; off; off >>= 1) m = fmaxf(m, __shfl_xor(m, off, 64));
        float ex = act ? expf(v - m) : 0.f;
        float s = ex;
#pragma unroll
        for (int off = 32; off; off >>= 1) s += __shfl_xor(s, off, 64);
        if (act) out[node * C_DIM + lane] = v - m - logf(s);
    }
}

extern "C" void kernel_launch(void* const* d_in, const int* in_sizes, int n_in,
                              void* d_out, int out_size, void* d_ws, size_t ws_size,
                              hipStream_t stream) {
    const float* x  = (const float*)d_in[0];
    const int*   ei = (const int*)d_in[1];
    const float* w  = (const float*)d_in[2];
    const float* W1 = (const float*)d_in[3];
    const float* b1 = (const float*)d_in[4];
    const float* W2 = (const float*)d_in[5];
    const float* b2 = (const float*)d_in[6];
    float* out = (float*)d_out;

    float* wsf = (float*)d_ws;
    int*   wsi = (int*)d_ws;
    float* dinv       = wsf + OFF_DINV;
    int*   bucketBase = wsi + OFF_BB;
    int*   H          = wsi + OFF_H;
    int*   blockBase  = wsi + OFF_BLB;
    int2*  rec        = (int2*)(wsi + OFF_REC);
    float* h1         = wsf + OFF_H1;
    float* h2         = wsf + OFF_H1;   // aliases h1 (dead after k_agg1)
    float* agg1       = wsf + OFF_AGG1;

    // CSR-by-bucket build (no global atomics anywhere)
    k_hist2d<<<NBE, 512, 0, stream>>>(ei, H);
    k_scan2d<<<1, 512, 0, stream>>>(H, bucketBase, blockBase);
    k_scatter<<<NBE, 512, 0, stream>>>(ei, w, blockBase, rec);
    k_deg<<<NB, 512, 0, stream>>>(bucketBase, rec, dinv);
    k_coeff<<<NB, 512, 0, stream>>>(bucketBase, dinv, rec);

    // layer 1
    k_mm1<<<512, 256, 0, stream>>>(x, W1, h1);
    k_agg1<<<NB, 512, 0, stream>>>(bucketBase, rec, dinv, h1, agg1);

    // layer 2 (+ fused bias/log-softmax epilogue)
    k_mm2<<<512, 256, 0, stream>>>(agg1, b1, W2, h2);
    k_agg2<<<NB, 512, 0, stream>>>(bucketBase, rec, dinv, h2, b2, out);
}

// Round 4
// 388.697 us; speedup vs baseline: 3.6041x; 3.6041x over previous
//
#include <hip/hip_runtime.h>
#include <math.h>

#define N_NODES 100000
#define N_EDGES 1600000
#define C_DIM 40

#define BSZ 256                           // nodes per bucket
#define NB  ((N_NODES + BSZ - 1) / BSZ)   // 391
#define EB  4096                          // edges per hist/scatter block
#define NBE ((N_EDGES + EB - 1) / EB)     // 391

// ---------------- workspace layout (4-byte units) ----------------
#define OFF_DINV 0                        // float[100000]
#define OFF_BB   100000                   // int[NB+1]
#define OFF_ROW  100400                   // int[N+1]
#define OFF_H    200402                   // int[NBE*NB] counts -> (in-place) per-(block,bucket) bases
#define OFF_REC2 353284                   // int2[E] sorted records (even -> 8B aligned)
#define OFF_H1   3753284                  // float[N*64]; unsorted rec aliases this; h2 aliases too
#define OFF_AGG1 10153284                 // float[N*64]
// total ~16.55M floats = 66 MB

__device__ inline float rlane(float v, int k) {
    return __int_as_float(__builtin_amdgcn_readlane(__float_as_int(v), k));
}

// ---------- per-block bucket histogram: H[b][j] ----------
__global__ __launch_bounds__(512) void k_hist2d(const int* __restrict__ ei, int* __restrict__ H) {
    __shared__ int bins[NB];
    int t = threadIdx.x, b = blockIdx.x;
    for (int i = t; i < NB; i += 512) bins[i] = 0;
    __syncthreads();
    int base = b * EB;
    for (int i = t; i < EB; i += 512) {
        int e = base + i;
        if (e < N_EDGES) atomicAdd(&bins[ei[N_EDGES + e] >> 8], 1);
    }
    __syncthreads();
    for (int i = t; i < NB; i += 512) H[b * NB + i] = bins[i];
}

// ---------- bucketBase = exclusive scan of column sums (1 block) ----------
__global__ __launch_bounds__(512) void k_bucketsum(const int* __restrict__ H,
                                                   int* __restrict__ bucketBase,
                                                   int* __restrict__ rowStart) {
    __shared__ int sd[512];
    int t = threadIdx.x;
    int val = 0;
    if (t < NB)
        for (int b = 0; b < NBE; ++b) val += H[b * NB + t];
    sd[t] = val;
    __syncthreads();
    for (int off = 1; off < 512; off <<= 1) {
        int v = (t >= off) ? sd[t - off] : 0;
        __syncthreads();
        sd[t] += v;
        __syncthreads();
    }
    if (t < NB) bucketBase[t] = sd[t] - val;
    if (t == NB - 1) bucketBase[NB] = sd[t];
    if (t == 0) rowStart[N_NODES] = N_EDGES;
}

// ---------- column scan: H[b][j] -> bucketBase[j] + prefix_b (in place) ----------
__global__ __launch_bounds__(512) void k_colscan(int* __restrict__ H,
                                                 const int* __restrict__ bucketBase) {
    __shared__ int sd[512];
    int t = threadIdx.x, j = blockIdx.x;
    int val = (t < NBE) ? H[t * NB + j] : 0;
    sd[t] = val;
    __syncthreads();
    for (int off = 1; off < 512; off <<= 1) {
        int v = (t >= off) ? sd[t - off] : 0;
        __syncthreads();
        sd[t] += v;
        __syncthreads();
    }
    if (t < NBE) H[t * NB + j] = bucketBase[j] + sd[t] - val;
}

// ---------- scatter into bucket regions (LDS cursors, no global atomics) ----------
__global__ __launch_bounds__(512) void k_scatter(const int* __restrict__ ei,
                                                 const float* __restrict__ w,
                                                 const int* __restrict__ blockBase,
                                                 int2* __restrict__ rec) {
    __shared__ int bases[NB];
    __shared__ int cur[NB];
    int t = threadIdx.x, b = blockIdx.x;
    for (int i = t; i < NB; i += 512) { bases[i] = blockBase[b * NB + i]; cur[i] = 0; }
    __syncthreads();
    int base = b * EB;
    for (int i = t; i < EB; i += 512) {
        int e = base + i;
        if (e < N_EDGES) {
            int s = ei[e], d = ei[N_EDGES + e];
            float wv = w[e];
            int bin = d >> 8;
            int pos = bases[bin] + atomicAdd(&cur[bin], 1);
            rec[pos] = make_int2(s | ((d & 255) << 17), __float_as_int(wv));
        }
    }
}

// ---------- per-bucket counting sort by local dst + deg/dinv + dst-side coeff ----------
__global__ __launch_bounds__(512) void k_bsort(const int* __restrict__ bucketBase,
                                               const int2* __restrict__ rec,
                                               int2* __restrict__ rec2,
                                               float* __restrict__ dinv,
                                               int* __restrict__ rowStart) {
    __shared__ int   cnt[256];
    __shared__ float wsum[256];   // w sums, then reused as local dinv
    __shared__ int   cur[256];
    __shared__ int   sd[512];
    int t = threadIdx.x, b = blockIdx.x;
    if (t < 256) { cnt[t] = 0; wsum[t] = 0.f; }
    __syncthreads();
    int r0 = bucketBase[b], r1 = bucketBase[b + 1];
    for (int i = r0 + t; i < r1; i += 512) {
        int2 rv = rec[i];
        int l = (rv.x >> 17) & 255;
        atomicAdd(&cnt[l], 1);
        atomicAdd(&wsum[l], __int_as_float(rv.y));
    }
    __syncthreads();
    int val = (t < 256) ? cnt[t] : 0;
    sd[t] = val;
    __syncthreads();
    for (int off = 1; off < 512; off <<= 1) {
        int v = (t >= off) ? sd[t - off] : 0;
        __syncthreads();
        sd[t] += v;
        __syncthreads();
    }
    float dloc = 0.f;
    if (t < 256) {
        int excl = sd[t] - val;
        cur[t] = excl;
        int node = b * BSZ + t;
        dloc = rsqrtf(1.f + wsum[t]);
        if (node < N_NODES) {
            rowStart[node] = r0 + excl;
            dinv[node] = dloc;
        }
    }
    __syncthreads();
    if (t < 256) wsum[t] = dloc;   // reuse as local dinv
    __syncthreads();
    for (int i = r0 + t; i < r1; i += 512) {
        int2 rv = rec[i];
        int l = (rv.x >> 17) & 255;
        float cpart = __int_as_float(rv.y) * wsum[l];   // w * dinv[dst]
        int pos = r0 + atomicAdd(&cur[l], 1);
        rec2[pos] = make_int2(rv.x & 0x1FFFF, __float_as_int(cpart));
    }
}

// ---------- finish coeff: *= dinv[src] (linear pass, dinv is L2-resident) ----------
__global__ __launch_bounds__(512) void k_coeff(const float* __restrict__ dinv,
                                               int2* __restrict__ rec2) {
    int i = blockIdx.x * 512 + threadIdx.x;
    if (i < N_EDGES) {
        int2 rv = rec2[i];
        rv.y = __float_as_int(__int_as_float(rv.y) * dinv[rv.x]);
        rec2[i] = rv;
    }
}

// ---------- h1 = x @ W1 : W column in regs, readlane broadcast ----------
__global__ __launch_bounds__(256) void k_mm1(const float* __restrict__ x,
                                             const float* __restrict__ W1,
                                             float* __restrict__ h1) {
    int t = threadIdx.x, lane = t & 63, wv = t >> 6;
    int wid = blockIdx.x * 4 + wv, nw = gridDim.x * 4;
    float Wc[64];
#pragma unroll
    for (int k = 0; k < 64; ++k) Wc[k] = W1[k * 64 + lane];
    for (int r0 = wid * 4; r0 < N_NODES; r0 += nw * 4) {
        float x0 = x[(r0 + 0) * 64 + lane];
        float x1 = x[(r0 + 1) * 64 + lane];
        float x2 = x[(r0 + 2) * 64 + lane];
        float x3 = x[(r0 + 3) * 64 + lane];
        float a0 = 0.f, a1 = 0.f, a2 = 0.f, a3 = 0.f;
#pragma unroll
        for (int k = 0; k < 64; ++k) {
            float wk = Wc[k];
            a0 = fmaf(rlane(x0, k), wk, a0);
            a1 = fmaf(rlane(x1, k), wk, a1);
            a2 = fmaf(rlane(x2, k), wk, a2);
            a3 = fmaf(rlane(x3, k), wk, a3);
        }
        h1[(r0 + 0) * 64 + lane] = a0;
        h1[(r0 + 1) * 64 + lane] = a1;
        h1[(r0 + 2) * 64 + lane] = a2;
        h1[(r0 + 3) * 64 + lane] = a3;
    }
}

// ---------- agg1: CSR gather, wave per node, lane = col, 4-wide unroll ----------
__global__ __launch_bounds__(256) void k_agg1(const int* __restrict__ rowStart,
                                              const int2* __restrict__ rec2,
                                              const float* __restrict__ dinv,
                                              const float* __restrict__ h1,
                                              float* __restrict__ agg1) {
    int t = threadIdx.x, lane = t & 63;
    int node = blockIdx.x * 4 + (t >> 6);
    if (node >= N_NODES) return;
    float dn = dinv[node];
    float acc = h1[node * 64 + lane] * dn * dn;  // self loop
    int s0 = rowStart[node], s1 = rowStart[node + 1];
    for (int base = s0; base < s1; base += 64) {
        int idx = base + lane;
        int2 ev = (idx < s1) ? rec2[idx] : make_int2(0, 0);
        int cnt = min(64, s1 - base);
        int j = 0;
        for (; j + 3 < cnt; j += 4) {
            int   s0i = __shfl(ev.x, j, 64),     s1i = __shfl(ev.x, j + 1, 64);
            int   s2i = __shfl(ev.x, j + 2, 64), s3i = __shfl(ev.x, j + 3, 64);
            float c0 = __int_as_float(__shfl(ev.y, j, 64));
            float c1 = __int_as_float(__shfl(ev.y, j + 1, 64));
            float c2 = __int_as_float(__shfl(ev.y, j + 2, 64));
            float c3 = __int_as_float(__shfl(ev.y, j + 3, 64));
            float v0 = h1[s0i * 64 + lane], v1 = h1[s1i * 64 + lane];
            float v2 = h1[s2i * 64 + lane], v3 = h1[s3i * 64 + lane];
            acc = fmaf(v0, c0, acc);
            acc = fmaf(v1, c1, acc);
            acc = fmaf(v2, c2, acc);
            acc = fmaf(v3, c3, acc);
        }
        for (; j < cnt; ++j) {
            int ss = __shfl(ev.x, j, 64);
            float cc = __int_as_float(__shfl(ev.y, j, 64));
            acc = fmaf(h1[ss * 64 + lane], cc, acc);
        }
    }
    agg1[node * 64 + lane] = acc;
}

// ---------- h2 = relu(agg1 + b1) @ W2 ----------
__global__ __launch_bounds__(256) void k_mm2(const float* __restrict__ agg1,
                                             const float* __restrict__ b1,
                                             const float* __restrict__ W2,
                                             float* __restrict__ h2) {
    int t = threadIdx.x, lane = t & 63, wv = t >> 6;
    int wid = blockIdx.x * 4 + wv, nw = gridDim.x * 4;
    bool act = lane < C_DIM;
    float Wc[64];
#pragma unroll
    for (int k = 0; k < 64; ++k) Wc[k] = act ? W2[k * C_DIM + lane] : 0.f;
    float bv = b1[lane];
    for (int r0 = wid * 4; r0 < N_NODES; r0 += nw * 4) {
        float x0 = fmaxf(agg1[(r0 + 0) * 64 + lane] + bv, 0.f);
        float x1 = fmaxf(agg1[(r0 + 1) * 64 + lane] + bv, 0.f);
        float x2 = fmaxf(agg1[(r0 + 2) * 64 + lane] + bv, 0.f);
        float x3 = fmaxf(agg1[(r0 + 3) * 64 + lane] + bv, 0.f);
        float a0 = 0.f, a1 = 0.f, a2 = 0.f, a3 = 0.f;
#pragma unroll
        for (int k = 0; k < 64; ++k) {
            float wk = Wc[k];
            a0 = fmaf(rlane(x0, k), wk, a0);
            a1 = fmaf(rlane(x1, k), wk, a1);
            a2 = fmaf(rlane(x2, k), wk, a2);
            a3 = fmaf(rlane(x3, k), wk, a3);
        }
        if (act) {
            h2[(r0 + 0) * C_DIM + lane] = a0;
            h2[(r0 + 1) * C_DIM + lane] = a1;
            h2[(r0 + 2) * C_DIM + lane] = a2;
            h2[(r0 + 3) * C_DIM + lane] = a3;
        }
    }
}

// ---------- agg2 + self-loop + bias + log_softmax fused, wave per node ----------
__global__ __launch_bounds__(256) void k_agg2(const int* __restrict__ rowStart,
                                              const int2* __restrict__ rec2,
                                              const float* __restrict__ dinv,
                                              const float* __restrict__ h2,
                                              const float* __restrict__ b2,
                                              float* __restrict__ out) {
    int t = threadIdx.x, lane = t & 63;
    int node = blockIdx.x * 4 + (t >> 6);
    if (node >= N_NODES) return;
    bool act = lane < C_DIM;
    float dn = dinv[node];
    float acc = act ? h2[node * C_DIM + lane] * dn * dn : 0.f;  // self loop
    int s0 = rowStart[node], s1 = rowStart[node + 1];
    for (int base = s0; base < s1; base += 64) {
        int idx = base + lane;
        int2 ev = (idx < s1) ? rec2[idx] : make_int2(0, 0);
        int cnt = min(64, s1 - base);
        int j = 0;
        for (; j + 3 < cnt; j += 4) {
            int   s0i = __shfl(ev.x, j, 64),     s1i = __shfl(ev.x, j + 1, 64);
            int   s2i = __shfl(ev.x, j + 2, 64), s3i = __shfl(ev.x, j + 3, 64);
            float c0 = __int_as_float(__shfl(ev.y, j, 64));
            float c1 = __int_as_float(__shfl(ev.y, j + 1, 64));
            float c2 = __int_as_float(__shfl(ev.y, j + 2, 64));
            float c3 = __int_as_float(__shfl(ev.y, j + 3, 64));
            if (act) {
                float v0 = h2[s0i * C_DIM + lane], v1 = h2[s1i * C_DIM + lane];
                float v2 = h2[s2i * C_DIM + lane], v3 = h2[s3i * C_DIM + lane];
                acc = fmaf(v0, c0, acc);
                acc = fmaf(v1, c1, acc);
                acc = fmaf(v2, c2, acc);
                acc = fmaf(v3, c3, acc);
            }
        }
        for (; j < cnt; ++j) {
            int ss = __shfl(ev.x, j, 64);
            float cc = __int_as_float(__shfl(ev.y, j, 64));
            if (act) acc = fmaf(h2[ss * C_DIM + lane], cc, acc);
        }
    }
    float v = act ? acc + b2[lane] : -INFINITY;
    float m = v;
#pragma unroll
    for (int off = 32; off; off >>= 1) m = fmaxf(m, __shfl_xor(m, off, 64));
    float ex = act ? expf(v - m) : 0.f;
    float s = ex;
#pragma unroll
    for (int off = 32; off; off >>= 1) s += __shfl_xor(s, off, 64);
    if (act) out[node * C_DIM + lane] = v - m - logf(s);
}

extern "C" void kernel_launch(void* const* d_in, const int* in_sizes, int n_in,
                              void* d_out, int out_size, void* d_ws, size_t ws_size,
                              hipStream_t stream) {
    const float* x  = (const float*)d_in[0];
    const int*   ei = (const int*)d_in[1];
    const float* w  = (const float*)d_in[2];
    const float* W1 = (const float*)d_in[3];
    const float* b1 = (const float*)d_in[4];
    const float* W2 = (const float*)d_in[5];
    const float* b2 = (const float*)d_in[6];
    float* out = (float*)d_out;

    float* wsf = (float*)d_ws;
    int*   wsi = (int*)d_ws;
    float* dinv       = wsf + OFF_DINV;
    int*   bucketBase = wsi + OFF_BB;
    int*   rowStart   = wsi + OFF_ROW;
    int*   H          = wsi + OFF_H;       // counts -> bases (in place)
    int2*  rec2       = (int2*)(wsi + OFF_REC2);
    int2*  rec        = (int2*)(wsi + OFF_H1);  // unsorted; dead before h1 written
    float* h1         = wsf + OFF_H1;
    float* h2         = wsf + OFF_H1;      // aliases h1 (dead after k_agg1)
    float* agg1       = wsf + OFF_AGG1;

    // CSR build — zero global atomics
    k_hist2d<<<NBE, 512, 0, stream>>>(ei, H);
    k_bucketsum<<<1, 512, 0, stream>>>(H, bucketBase, rowStart);
    k_colscan<<<NB, 512, 0, stream>>>(H, bucketBase);
    k_scatter<<<NBE, 512, 0, stream>>>(ei, w, H, rec);
    k_bsort<<<NB, 512, 0, stream>>>(bucketBase, rec, rec2, dinv, rowStart);
    k_coeff<<<(N_EDGES + 511) / 512, 512, 0, stream>>>(dinv, rec2);

    // layer 1
    k_mm1<<<512, 256, 0, stream>>>(x, W1, h1);
    k_agg1<<<(N_NODES + 3) / 4, 256, 0, stream>>>(rowStart, rec2, dinv, h1, agg1);

    // layer 2 (+ fused bias/log-softmax epilogue)
    k_mm2<<<512, 256, 0, stream>>>(agg1, b1, W2, h2);
    k_agg2<<<(N_NODES + 3) / 4, 256, 0, stream>>>(rowStart, rec2, dinv, h2, b2, out);
}

// Round 5
// 346.441 us; speedup vs baseline: 4.0437x; 1.1220x over previous
//
#include <hip/hip_runtime.h>
#include <math.h>

#define N_NODES 100000
#define N_EDGES 1600000
#define C_DIM 40

#define BSZ 256                           // nodes per bucket
#define NB  ((N_NODES + BSZ - 1) / BSZ)   // 391
#define EB  4096                          // edges per hist/scatter block
#define NBE ((N_EDGES + EB - 1) / EB)     // 391

// ---------------- workspace layout (4-byte units) ----------------
#define OFF_DINV 0                        // float[100000]
#define OFF_BB   100000                   // int[NB+1]
#define OFF_ROW  100400                   // int[N+1]
#define OFF_H    200402                   // int[NBE*NB]
#define OFF_REC2 353284                   // int2[E] sorted records (even -> 8B aligned)
#define OFF_H1P  3553284                  // ushort[N*64] bf16 rows; unsorted rec + h2p alias here
#define OFF_AGG1 6753284                  // float[N*64]
// total ~13.15M ints = 52.6 MB (< 66 MB used previously)

__device__ inline float rlane(float v, int k) {
    return __int_as_float(__builtin_amdgcn_readlane(__float_as_int(v), k));
}
__device__ inline unsigned short f2bf(float f) {
    unsigned int u = __float_as_uint(f);
    u += 0x7FFF + ((u >> 16) & 1);        // round to nearest even
    return (unsigned short)(u >> 16);
}
__device__ inline float bf2f(unsigned short h) {
    return __uint_as_float(((unsigned int)h) << 16);
}

// ---------- per-block bucket histogram: H[b][j] ----------
__global__ __launch_bounds__(512) void k_hist2d(const int* __restrict__ ei, int* __restrict__ H) {
    __shared__ int bins[NB];
    int t = threadIdx.x, b = blockIdx.x;
    for (int i = t; i < NB; i += 512) bins[i] = 0;
    __syncthreads();
    int base = b * EB;
    for (int i = t; i < EB; i += 512) {
        int e = base + i;
        if (e < N_EDGES) atomicAdd(&bins[ei[N_EDGES + e] >> 8], 1);
    }
    __syncthreads();
    for (int i = t; i < NB; i += 512) H[b * NB + i] = bins[i];
}

// ---------- bucketBase = exclusive scan of column sums (1 block) ----------
__global__ __launch_bounds__(512) void k_bucketsum(const int* __restrict__ H,
                                                   int* __restrict__ bucketBase,
                                                   int* __restrict__ rowStart) {
    __shared__ int sd[512];
    int t = threadIdx.x;
    int val = 0;
    if (t < NB)
        for (int b = 0; b < NBE; ++b) val += H[b * NB + t];
    sd[t] = val;
    __syncthreads();
    for (int off = 1; off < 512; off <<= 1) {
        int v = (t >= off) ? sd[t - off] : 0;
        __syncthreads();
        sd[t] += v;
        __syncthreads();
    }
    if (t < NB) bucketBase[t] = sd[t] - val;
    if (t == NB - 1) bucketBase[NB] = sd[t];
    if (t == 0) rowStart[N_NODES] = N_EDGES;
}

// ---------- column scan: H[b][j] -> bucketBase[j] + prefix_b (in place) ----------
__global__ __launch_bounds__(512) void k_colscan(int* __restrict__ H,
                                                 const int* __restrict__ bucketBase) {
    __shared__ int sd[512];
    int t = threadIdx.x, j = blockIdx.x;
    int val = (t < NBE) ? H[t * NB + j] : 0;
    sd[t] = val;
    __syncthreads();
    for (int off = 1; off < 512; off <<= 1) {
        int v = (t >= off) ? sd[t - off] : 0;
        __syncthreads();
        sd[t] += v;
        __syncthreads();
    }
    if (t < NBE) H[t * NB + j] = bucketBase[j] + sd[t] - val;
}

// ---------- scatter into bucket regions (LDS cursors, no global atomics) ----------
__global__ __launch_bounds__(512) void k_scatter(const int* __restrict__ ei,
                                                 const float* __restrict__ w,
                                                 const int* __restrict__ blockBase,
                                                 int2* __restrict__ rec) {
    __shared__ int bases[NB];
    __shared__ int cur[NB];
    int t = threadIdx.x, b = blockIdx.x;
    for (int i = t; i < NB; i += 512) { bases[i] = blockBase[b * NB + i]; cur[i] = 0; }
    __syncthreads();
    int base = b * EB;
    for (int i = t; i < EB; i += 512) {
        int e = base + i;
        if (e < N_EDGES) {
            int s = ei[e], d = ei[N_EDGES + e];
            float wv = w[e];
            int bin = d >> 8;
            int pos = bases[bin] + atomicAdd(&cur[bin], 1);
            rec[pos] = make_int2(s | ((d & 255) << 17), __float_as_int(wv));
        }
    }
}

// ---------- per-bucket counting sort by local dst + deg/dinv; payload = w*dinv[dst] ----------
__global__ __launch_bounds__(512) void k_bsort(const int* __restrict__ bucketBase,
                                               const int2* __restrict__ rec,
                                               int2* __restrict__ rec2,
                                               float* __restrict__ dinv,
                                               int* __restrict__ rowStart) {
    __shared__ int   cnt[256];
    __shared__ float wsum[256];   // w sums, then reused as local dinv
    __shared__ int   cur[256];
    __shared__ int   sd[512];
    int t = threadIdx.x, b = blockIdx.x;
    if (t < 256) { cnt[t] = 0; wsum[t] = 0.f; }
    __syncthreads();
    int r0 = bucketBase[b], r1 = bucketBase[b + 1];
    for (int i = r0 + t; i < r1; i += 512) {
        int2 rv = rec[i];
        int l = (rv.x >> 17) & 255;
        atomicAdd(&cnt[l], 1);
        atomicAdd(&wsum[l], __int_as_float(rv.y));
    }
    __syncthreads();
    int val = (t < 256) ? cnt[t] : 0;
    sd[t] = val;
    __syncthreads();
    for (int off = 1; off < 512; off <<= 1) {
        int v = (t >= off) ? sd[t - off] : 0;
        __syncthreads();
        sd[t] += v;
        __syncthreads();
    }
    float dloc = 0.f;
    if (t < 256) {
        int excl = sd[t] - val;
        cur[t] = excl;
        int node = b * BSZ + t;
        dloc = rsqrtf(1.f + wsum[t]);
        if (node < N_NODES) {
            rowStart[node] = r0 + excl;
            dinv[node] = dloc;
        }
    }
    __syncthreads();
    if (t < 256) wsum[t] = dloc;   // reuse as local dinv
    __syncthreads();
    for (int i = r0 + t; i < r1; i += 512) {
        int2 rv = rec[i];
        int l = (rv.x >> 17) & 255;
        float cpart = __int_as_float(rv.y) * wsum[l];   // w * dinv[dst]
        int pos = r0 + atomicAdd(&cur[l], 1);
        rec2[pos] = make_int2(rv.x & 0x1FFFF, __float_as_int(cpart));
    }
}

// ---------- h1' = (x @ W1) * dinv[row], stored bf16 ----------
__global__ __launch_bounds__(256) void k_mm1(const float* __restrict__ x,
                                             const float* __restrict__ W1,
                                             const float* __restrict__ dinv,
                                             unsigned short* __restrict__ h1p) {
    int t = threadIdx.x, lane = t & 63, wv = t >> 6;
    int wid = blockIdx.x * 4 + wv, nw = gridDim.x * 4;
    float Wc[64];
#pragma unroll
    for (int k = 0; k < 64; ++k) Wc[k] = W1[k * 64 + lane];
    for (int r0 = wid * 4; r0 < N_NODES; r0 += nw * 4) {
        float x0 = x[(r0 + 0) * 64 + lane];
        float x1 = x[(r0 + 1) * 64 + lane];
        float x2 = x[(r0 + 2) * 64 + lane];
        float x3 = x[(r0 + 3) * 64 + lane];
        float d0 = dinv[r0 + 0], d1 = dinv[r0 + 1], d2 = dinv[r0 + 2], d3 = dinv[r0 + 3];
        float a0 = 0.f, a1 = 0.f, a2 = 0.f, a3 = 0.f;
#pragma unroll
        for (int k = 0; k < 64; ++k) {
            float wk = Wc[k];
            a0 = fmaf(rlane(x0, k), wk, a0);
            a1 = fmaf(rlane(x1, k), wk, a1);
            a2 = fmaf(rlane(x2, k), wk, a2);
            a3 = fmaf(rlane(x3, k), wk, a3);
        }
        h1p[(r0 + 0) * 64 + lane] = f2bf(a0 * d0);
        h1p[(r0 + 1) * 64 + lane] = f2bf(a1 * d1);
        h1p[(r0 + 2) * 64 + lane] = f2bf(a2 * d2);
        h1p[(r0 + 3) * 64 + lane] = f2bf(a3 * d3);
    }
}

// ---------- agg1: CSR gather of bf16 rows; agg1 = sum + self-loop (fp32 out) ----------
__global__ __launch_bounds__(256) void k_agg1(const int* __restrict__ rowStart,
                                              const int2* __restrict__ rec2,
                                              const float* __restrict__ dinv,
                                              const unsigned short* __restrict__ h1p,
                                              float* __restrict__ agg1) {
    int t = threadIdx.x, lane = t & 63;
    int node = blockIdx.x * 4 + (t >> 6);
    if (node >= N_NODES) return;
    float dn = dinv[node];
    float acc = bf2f(h1p[node * 64 + lane]) * dn;  // self loop: h1'*dinv = h1*dinv^2
    int s0 = rowStart[node], s1 = rowStart[node + 1];
    for (int base = s0; base < s1; base += 64) {
        int idx = base + lane;
        int2 ev = (idx < s1) ? rec2[idx] : make_int2(0, 0);
        int cnt = min(64, s1 - base);
        int j = 0;
        for (; j + 3 < cnt; j += 4) {
            int   i0 = __shfl(ev.x, j, 64),     i1 = __shfl(ev.x, j + 1, 64);
            int   i2 = __shfl(ev.x, j + 2, 64), i3 = __shfl(ev.x, j + 3, 64);
            float c0 = __int_as_float(__shfl(ev.y, j, 64));
            float c1 = __int_as_float(__shfl(ev.y, j + 1, 64));
            float c2 = __int_as_float(__shfl(ev.y, j + 2, 64));
            float c3 = __int_as_float(__shfl(ev.y, j + 3, 64));
            float v0 = bf2f(h1p[i0 * 64 + lane]), v1 = bf2f(h1p[i1 * 64 + lane]);
            float v2 = bf2f(h1p[i2 * 64 + lane]), v3 = bf2f(h1p[i3 * 64 + lane]);
            acc = fmaf(v0, c0, acc);
            acc = fmaf(v1, c1, acc);
            acc = fmaf(v2, c2, acc);
            acc = fmaf(v3, c3, acc);
        }
        for (; j < cnt; ++j) {
            int ss = __shfl(ev.x, j, 64);
            float cc = __int_as_float(__shfl(ev.y, j, 64));
            acc = fmaf(bf2f(h1p[ss * 64 + lane]), cc, acc);
        }
    }
    agg1[node * 64 + lane] = acc;
}

// ---------- h2' = (relu(agg1+b1) @ W2) * dinv[row], stored bf16 ----------
__global__ __launch_bounds__(256) void k_mm2(const float* __restrict__ agg1,
                                             const float* __restrict__ b1,
                                             const float* __restrict__ W2,
                                             const float* __restrict__ dinv,
                                             unsigned short* __restrict__ h2p) {
    int t = threadIdx.x, lane = t & 63, wv = t >> 6;
    int wid = blockIdx.x * 4 + wv, nw = gridDim.x * 4;
    bool act = lane < C_DIM;
    float Wc[64];
#pragma unroll
    for (int k = 0; k < 64; ++k) Wc[k] = act ? W2[k * C_DIM + lane] : 0.f;
    float bv = b1[lane];
    for (int r0 = wid * 4; r0 < N_NODES; r0 += nw * 4) {
        float x0 = fmaxf(agg1[(r0 + 0) * 64 + lane] + bv, 0.f);
        float x1 = fmaxf(agg1[(r0 + 1) * 64 + lane] + bv, 0.f);
        float x2 = fmaxf(agg1[(r0 + 2) * 64 + lane] + bv, 0.f);
        float x3 = fmaxf(agg1[(r0 + 3) * 64 + lane] + bv, 0.f);
        float d0 = dinv[r0 + 0], d1 = dinv[r0 + 1], d2 = dinv[r0 + 2], d3 = dinv[r0 + 3];
        float a0 = 0.f, a1 = 0.f, a2 = 0.f, a3 = 0.f;
#pragma unroll
        for (int k = 0; k < 64; ++k) {
            float wk = Wc[k];
            a0 = fmaf(rlane(x0, k), wk, a0);
            a1 = fmaf(rlane(x1, k), wk, a1);
            a2 = fmaf(rlane(x2, k), wk, a2);
            a3 = fmaf(rlane(x3, k), wk, a3);
        }
        if (act) {
            h2p[(r0 + 0) * C_DIM + lane] = f2bf(a0 * d0);
            h2p[(r0 + 1) * C_DIM + lane] = f2bf(a1 * d1);
            h2p[(r0 + 2) * C_DIM + lane] = f2bf(a2 * d2);
            h2p[(r0 + 3) * C_DIM + lane] = f2bf(a3 * d3);
        }
    }
}

// ---------- agg2 + self-loop + bias + log_softmax fused, wave per node ----------
__global__ __launch_bounds__(256) void k_agg2(const int* __restrict__ rowStart,
                                              const int2* __restrict__ rec2,
                                              const float* __restrict__ dinv,
                                              const unsigned short* __restrict__ h2p,
                                              const float* __restrict__ b2,
                                              float* __restrict__ out) {
    int t = threadIdx.x, lane = t & 63;
    int node = blockIdx.x * 4 + (t >> 6);
    if (node >= N_NODES) return;
    bool act = lane < C_DIM;
    float dn = dinv[node];
    float acc = act ? bf2f(h2p[node * C_DIM + lane]) * dn : 0.f;  // self loop
    int s0 = rowStart[node], s1 = rowStart[node + 1];
    for (int base = s0; base < s1; base += 64) {
        int idx = base + lane;
        int2 ev = (idx < s1) ? rec2[idx] : make_int2(0, 0);
        int cnt = min(64, s1 - base);
        int j = 0;
        for (; j + 3 < cnt; j += 4) {
            int   i0 = __shfl(ev.x, j, 64),     i1 = __shfl(ev.x, j + 1, 64);
            int   i2 = __shfl(ev.x, j + 2, 64), i3 = __shfl(ev.x, j + 3, 64);
            float c0 = __int_as_float(__shfl(ev.y, j, 64));
            float c1 = __int_as_float(__shfl(ev.y, j + 1, 64));
            float c2 = __int_as_float(__shfl(ev.y, j + 2, 64));
            float c3 = __int_as_float(__shfl(ev.y, j + 3, 64));
            if (act) {
                float v0 = bf2f(h2p[i0 * C_DIM + lane]), v1 = bf2f(h2p[i1 * C_DIM + lane]);
                float v2 = bf2f(h2p[i2 * C_DIM + lane]), v3 = bf2f(h2p[i3 * C_DIM + lane]);
                acc = fmaf(v0, c0, acc);
                acc = fmaf(v1, c1, acc);
                acc = fmaf(v2, c2, acc);
                acc = fmaf(v3, c3, acc);
            }
        }
        for (; j < cnt; ++j) {
            int ss = __shfl(ev.x, j, 64);
            float cc = __int_as_float(__shfl(ev.y, j, 64));
            if (act) acc = fmaf(bf2f(h2p[ss * C_DIM + lane]), cc, acc);
        }
    }
    float v = act ? acc + b2[lane] : -INFINITY;
    float m = v;
#pragma unroll
    for (int off = 32; off; off >>= 1) m = fmaxf(m, __shfl_xor(m, off, 64));
    float ex = act ? expf(v - m) : 0.f;
    float s = ex;
#pragma unroll
    for (int off = 32; off; off >>= 1) s += __shfl_xor(s, off, 64);
    if (act) out[node * C_DIM + lane] = v - m - logf(s);
}

extern "C" void kernel_launch(void* const* d_in, const int* in_sizes, int n_in,
                              void* d_out, int out_size, void* d_ws, size_t ws_size,
                              hipStream_t stream) {
    const float* x  = (const float*)d_in[0];
    const int*   ei = (const int*)d_in[1];
    const float* w  = (const float*)d_in[2];
    const float* W1 = (const float*)d_in[3];
    const float* b1 = (const float*)d_in[4];
    const float* W2 = (const float*)d_in[5];
    const float* b2 = (const float*)d_in[6];
    float* out = (float*)d_out;

    float* wsf = (float*)d_ws;
    int*   wsi = (int*)d_ws;
    float* dinv       = wsf + OFF_DINV;
    int*   bucketBase = wsi + OFF_BB;
    int*   rowStart   = wsi + OFF_ROW;
    int*   H          = wsi + OFF_H;
    int2*  rec2       = (int2*)(wsi + OFF_REC2);
    int2*  rec        = (int2*)(wsi + OFF_H1P);              // dead before h1p written
    unsigned short* h1p = (unsigned short*)(wsi + OFF_H1P);
    unsigned short* h2p = (unsigned short*)(wsi + OFF_H1P);  // h1p dead after k_agg1
    float* agg1       = wsf + OFF_AGG1;

    // CSR build — zero global atomics
    k_hist2d<<<NBE, 512, 0, stream>>>(ei, H);
    k_bucketsum<<<1, 512, 0, stream>>>(H, bucketBase, rowStart);
    k_colscan<<<NB, 512, 0, stream>>>(H, bucketBase);
    k_scatter<<<NBE, 512, 0, stream>>>(ei, w, H, rec);
    k_bsort<<<NB, 512, 0, stream>>>(bucketBase, rec, rec2, dinv, rowStart);

    // layer 1
    k_mm1<<<512, 256, 0, stream>>>(x, W1, dinv, h1p);
    k_agg1<<<(N_NODES + 3) / 4, 256, 0, stream>>>(rowStart, rec2, dinv, h1p, agg1);

    // layer 2 (+ fused bias/log-softmax epilogue)
    k_mm2<<<512, 256, 0, stream>>>(agg1, b1, W2, dinv, h2p);
    k_agg2<<<(N_NODES + 3) / 4, 256, 0, stream>>>(rowStart, rec2, dinv, h2p, b2, out);
}